// Round 9
// baseline (488.042 us; speedup 1.0000x reference)
//
#include <hip/hip_runtime.h>

// TV-L1 optical flow, B=4, 512x512, 20 iters — temporal blocking (ghost zones)
// R9 = R6 structure + pixel-PAIR processing with register mirrors.
//   256 blocks x 512 threads; 64x64 tile, 80x80 region (halo L=6/R=10),
//   5 fused iterations/launch, 4 launches. Each thread owns 7 pixel-PAIRS
//   (3200 pairs / 512 thr); u/pa/pb own-pair state mirrored in VGPRs, all
//   neighbor LDS traffic as aligned b128/b64 ops (~40% fewer LDS pipe cyc).
//   amdgpu_waves_per_eu(2,2) pins allocator at 2 waves/SIMD (256-VGPR
//   budget) to prevent the R7 heuristic-spill failure.
// LDS: su,spa,spb = 3 x 6400 x 8B = 153.6 KB. Row-only cone guards
// (R6-validated). Zero-padding via forcing u=p=0 off-image (pair-uniform).
// Last kernel skips the dead 20th p-update and fuses the 3x3 avgpool.

typedef float v2f __attribute__((ext_vector_type(2)));
typedef float v4f __attribute__((ext_vector_type(4)));

#define HH 512
#define WW 512
#define BB 4
constexpr int HW   = HH * WW;
constexpr int NTOT = BB * HW;
constexpr float EPS = 1e-8f;

#define T 64            // output tile edge
#define HALO_L 6        // left/top halo
#define REG 80          // region edge = 64 + 6 + 10
#define NPX (REG * REG) // 6400
#define NPAIR 3200      // pixel pairs per region
#define PPR 40          // pairs per row
#define TPB 512         // 8 waves
#define SLOTS 7         // ceil(3200/512); slot 6: tid<128 valid
#define NBLK 256        // 4 images x 8x8 tiles
#define XR 84           // x1 staging row stride (even-offset for float2)
#define XROWS 82
#define XN (XR * XROWS) // 6888 floats = 27.6 KB (aliases spa)
#define XPAIRS (XN / 2) // 3444
#define XPPR 42         // staging pairs per row
#define XSLOTS 7

__device__ __forceinline__ v2f lo2(v4f v) { v2f r; r.x = v.x; r.y = v.y; return r; }
__device__ __forceinline__ v2f hi2(v4f v) { v2f r; r.x = v.z; r.y = v.w; return r; }

// phase: 0 = first (u,p zero-init, write back), 1 = middle (load, write
// back), 2 = last (load, 5 u- + 4 p-phases, fused avgpool -> out).
__global__ void __launch_bounds__(TPB, 2)
__attribute__((amdgpu_waves_per_eu(2, 2)))
k_fused(const float* __restrict__ x,
        v2f* __restrict__ ug, float4* __restrict__ pg,
        const float* __restrict__ lam_p, const float* __restrict__ tau_p,
        const float* __restrict__ theta_p,
        const float* __restrict__ wxp, const float* __restrict__ wyp,
        float* __restrict__ out, int phase)
{
    __shared__ __align__(16) v2f su[NPX];    // (u1,u2)
    __shared__ __align__(16) v2f spa[NPX];   // (p11,p21); aliases x1 staging
    __shared__ __align__(16) v2f spb[NPX];   // (p12,p22)  -> 153.6 KB

    const int tid  = threadIdx.x;
    const int blk  = blockIdx.x;
    const int bimg = blk >> 6;
    const int t    = blk & 63;
    const int gi0  = (t >> 3) * T;
    const int gj0  = (t & 7) * T;

    const float lam = lam_p[0], theta = theta_p[0];
    const float r   = tau_p[0] / theta;
    const float tl  = theta * lam;
    const float wx0 = wxp[0], wx1 = wxp[1], wx2 = wxp[2];
    const float wy0 = wyp[0], wy1 = wyp[1], wy2 = wyp[2];

    const int gbase = bimg * HW;
    const float* x0p = x + (size_t)bimg * 2 * HW;
    const float* x1p = x0p + HW;

    int  lis[SLOTS];
    unsigned inbm = 0;                       // bit s = pair in-image
    v4f  ru4[SLOTS], rpa4[SLOTS], rpb4[SLOTS];  // own-pair mirrors
    v2f  x0v[SLOTS];

    // ---- pass 1a: stage x1 (84x82, zero-padded, float2 loads) ------------
    float* stg = (float*)spa;
    #pragma unroll
    for (int s = 0; s < XSLOTS; ++s) {
        int ip = tid + s * TPB;
        if (ip < XPAIRS) {
            int li = ip / XPPR, ljp = ip - li * XPPR;
            int gi = gi0 + li - (HALO_L + 1);        // rows gi0-7 .. gi0+74
            int gj = gj0 + 2 * ljp - (HALO_L + 2);   // cols gj0-8 .. gj0+74 (even)
            float2 v = make_float2(0.f, 0.f);
            if (((unsigned)gi < HH) & ((unsigned)gj < WW))
                v = *(const float2*)(x1p + gi * WW + gj);
            ((float2*)stg)[ip] = v;
        }
    }
    // ---- pass 1b: per-slot indices + state loads into mirrors ------------
    #pragma unroll
    for (int s = 0; s < SLOTS; ++s) {
        int p = tid + s * TPB;
        lis[s] = 255;
        v4f z4; z4.x = z4.y = z4.z = z4.w = 0.f;
        ru4[s] = z4; rpa4[s] = z4; rpb4[s] = z4;
        x0v[s] = (v2f)(0.f);
        if (p < NPAIR) {
            int li = p / PPR, ljp = p - li * PPR;
            lis[s] = li;
            int gi = gi0 + li - HALO_L, gj = gj0 + 2 * ljp - HALO_L;  // gj even
            bool in = ((unsigned)gi < HH) & ((unsigned)gj < WW);      // pair-uniform
            if (in) {
                inbm |= (1u << s);
                int gl = gi * WW + gj;
                x0v[s] = *(const v2f*)(x0p + gl);
                if (phase != 0) {
                    ru4[s] = *(const v4f*)(ug + gbase + gl);
                    float4 q0 = pg[gbase + gl];
                    float4 q1 = pg[gbase + gl + 1];
                    v4f pa; pa.x = q0.x; pa.y = q0.y; pa.z = q1.x; pa.w = q1.y;
                    v4f pb; pb.x = q0.z; pb.y = q0.w; pb.z = q1.z; pb.w = q1.w;
                    rpa4[s] = pa; rpb4[s] = pb;
                }
            }
        }
    }
    __syncthreads();

    // ---- pass 2: statics per pair from staged x1 -------------------------
    v4f  g4[SLOTS];                  // (gx0,gy0,gx1,gy1)
    v2f  rc2[SLOTS], nm2[SLOTS];
    #pragma unroll
    for (int s = 0; s < SLOTS; ++s) {
        int p = tid + s * TPB;
        if (p < NPAIR) {
            int li = lis[s], ljp = p - li * PPR, lj0 = 2 * ljp;
            int sc = (li + 1) * XR + lj0 + 2;    // px0 center in stg
            const float c6 = 1.f / 6.f;
            float gx0 = 0.f, gy0 = 0.f, gx1 = 0.f, gy1 = 0.f, ctr0 = 0.f, ctr1 = 0.f;
            #pragma unroll
            for (int dr = -1; dr <= 1; ++dr) {
                int b = sc + dr * XR;
                float2 eA = *(const float2*)(stg + b - 2);
                float2 eB = *(const float2*)(stg + b);
                float2 eC = *(const float2*)(stg + b + 2);
                float l0 = eA.y, c0 = eB.x, r0 = eB.y;   // px0 taps
                float l1 = eB.x, c1 = eB.y, r1 = eC.x;   // px1 taps
                float wgx = (dr == 0) ? 2.f : 1.f;
                gx0 += wgx * (r0 - l0);
                gx1 += wgx * (r1 - l1);
                if (dr != 0) {
                    float sgn = (float)dr;               // -1 top, +1 bottom
                    gy0 += sgn * (l0 + 2.f * c0 + r0);
                    gy1 += sgn * (l1 + 2.f * c1 + r1);
                } else { ctr0 = c0; ctr1 = c1; }
            }
            gx0 *= c6; gy0 *= c6; gx1 *= c6; gy1 *= c6;
            v4f g; g.x = gx0; g.y = gy0; g.z = gx1; g.w = gy1;
            g4[s] = g;
            v2f rc; rc.x = ctr0 - x0v[s].x; rc.y = ctr1 - x0v[s].y;
            rc2[s] = rc;
            v2f nm; nm.x = gx0 * gx0 + gy0 * gy0 + EPS;
            nm.y = gx1 * gx1 + gy1 * gy1 + EPS;
            nm2[s] = nm;
        }
    }
    __syncthreads();

    // ---- pass 3: fill LDS state (overwrites staging) ---------------------
    #pragma unroll
    for (int s = 0; s < SLOTS; ++s) {
        int p = tid + s * TPB;
        if (p < NPAIR) {
            int i = 2 * p;
            *(v4f*)(su  + i) = ru4[s];
            *(v4f*)(spa + i) = rpa4[s];
            *(v4f*)(spb + i) = rpb4[s];
        }
    }
    __syncthreads();

    // ---- 5 fused iterations ---------------------------------------------
    for (int k = 1; k <= 5; ++k) {
        // u-phase rows [k, REG-2k]; all columns (cone-safe, R6-validated)
        const int lo = k, hi_u = REG - 2 * k;
        #pragma unroll
        for (int s = 0; s < SLOTS; ++s) {
            int li = lis[s];
            if (li < lo || li > hi_u) continue;
            int i = 2 * (tid + s * TPB);
            v4f u = ru4[s];
            float rho0 = rc2[s].x + g4[s].x * u.x + g4[s].y * u.y;
            float rho1 = rc2[s].y + g4[s].z * u.z + g4[s].w * u.w;
            float th0 = tl * nm2[s].x, th1 = tl * nm2[s].y;
            float d0 = (fabsf(rho0) < th0) ? rho0 * __builtin_amdgcn_rcpf(nm2[s].x)
                                           : copysignf(tl, rho0);
            float d1 = (fabsf(rho1) < th1) ? rho1 * __builtin_amdgcn_rcpf(nm2[s].y)
                                           : copysignf(tl, rho1);
            v2f pal = spa[i - 1];
            v2f par = spa[i + 2];
            v4f pbt = *(v4f*)(spb + i - REG);
            v4f pbb = *(v4f*)(spb + i + REG);
            v4f pac = rpa4[s], pbc = rpb4[s];
            v2f div0 = wx0 * pal      + wx1 * lo2(pac) + wx2 * hi2(pac)
                     + wy0 * lo2(pbt) + wy1 * lo2(pbc) + wy2 * lo2(pbb);
            v2f div1 = wx0 * lo2(pac) + wx1 * hi2(pac) + wx2 * par
                     + wy0 * hi2(pbt) + wy1 * hi2(pbc) + wy2 * hi2(pbb);
            v2f nu0 = lo2(u); nu0.x -= d0 * g4[s].x; nu0.y -= d0 * g4[s].y;
            v2f nu1 = hi2(u); nu1.x -= d1 * g4[s].z; nu1.y -= d1 * g4[s].w;
            nu0 += theta * div0;
            nu1 += theta * div1;
            if (!((inbm >> s) & 1u)) { nu0 = (v2f)(0.f); nu1 = (v2f)(0.f); }
            v4f nu; nu.x = nu0.x; nu.y = nu0.y; nu.z = nu1.x; nu.w = nu1.y;
            ru4[s] = nu;
            *(v4f*)(su + i) = nu;
        }
        __syncthreads();
        if (phase == 2 && k == 5) break;   // 20th p-update is dead code

        // p-phase rows [k, REG-1-2k]
        const int hi_p = REG - 1 - 2 * k;
        #pragma unroll
        for (int s = 0; s < SLOTS; ++s) {
            int li = lis[s];
            if (li < lo || li > hi_p) continue;
            int i = 2 * (tid + s * TPB);
            v4f uc = ru4[s];
            v2f uE1 = su[i + 2];                 // right neighbor of px1
            v4f uS  = *(v4f*)(su + i + REG);
            v2f gx0 = hi2(uc) - lo2(uc);
            v2f gx1 = uE1 - hi2(uc);
            v2f gy0 = lo2(uS) - lo2(uc);
            v2f gy1 = hi2(uS) - hi2(uc);
            float dn00 = 1.f + r * (fabsf(gx0.x) + fabsf(gy0.x));
            float dn01 = 1.f + r * (fabsf(gx0.y) + fabsf(gy0.y));
            float dn10 = 1.f + r * (fabsf(gx1.x) + fabsf(gy1.x));
            float dn11 = 1.f + r * (fabsf(gx1.y) + fabsf(gy1.y));
            v2f id0; id0.x = __builtin_amdgcn_rcpf(dn00); id0.y = __builtin_amdgcn_rcpf(dn01);
            v2f id1; id1.x = __builtin_amdgcn_rcpf(dn10); id1.y = __builtin_amdgcn_rcpf(dn11);
            v2f npa0 = (lo2(rpa4[s]) + r * gx0) * id0;
            v2f npa1 = (hi2(rpa4[s]) + r * gx1) * id1;
            v2f npb0 = (lo2(rpb4[s]) + r * gy0) * id0;
            v2f npb1 = (hi2(rpb4[s]) + r * gy1) * id1;
            if (!((inbm >> s) & 1u)) {
                npa0 = (v2f)(0.f); npa1 = (v2f)(0.f);
                npb0 = (v2f)(0.f); npb1 = (v2f)(0.f);
            }
            v4f npa; npa.x = npa0.x; npa.y = npa0.y; npa.z = npa1.x; npa.w = npa1.y;
            v4f npb; npb.x = npb0.x; npb.y = npb0.y; npb.z = npb1.x; npb.w = npb1.y;
            rpa4[s] = npa; rpb4[s] = npb;
            *(v4f*)(spa + i) = npa;
            *(v4f*)(spb + i) = npb;
        }
        __syncthreads();
    }

    // ---- epilogue --------------------------------------------------------
    if (phase != 2) {
        // write back interior pairs (li in [6,69], ljp in [3,34])
        #pragma unroll
        for (int s = 0; s < SLOTS; ++s) {
            int p = tid + s * TPB;
            int li = lis[s];
            if ((unsigned)(li - HALO_L) >= T) continue;
            int ljp = p - li * PPR;
            if ((unsigned)(ljp - 3) >= 32) continue;
            int gl = (gi0 + li - HALO_L) * WW + (gj0 + 2 * ljp - HALO_L);
            *(v4f*)(ug + gbase + gl) = ru4[s];
            v4f pa = rpa4[s], pb = rpb4[s];
            pg[gbase + gl]     = make_float4(pa.x, pa.y, pb.x, pb.y);
            pg[gbase + gl + 1] = make_float4(pa.z, pa.w, pb.z, pb.w);
        }
    } else {
        // fused avgpool(3,1,1, /9 always) on u^20
        const float inv9 = 1.f / 9.f;
        #pragma unroll
        for (int s = 0; s < SLOTS; ++s) {
            int p = tid + s * TPB;
            int li = lis[s];
            if ((unsigned)(li - HALO_L) >= T) continue;
            int ljp = p - li * PPR;
            if ((unsigned)(ljp - 3) >= 32) continue;
            int i = 2 * p;
            v2f aL = su[i - REG - 1]; v4f aC = *(v4f*)(su + i - REG); v2f aR = su[i - REG + 2];
            v2f bL = su[i - 1];       v4f bC = ru4[s];                v2f bR = su[i + 2];
            v2f cL = su[i + REG - 1]; v4f cC = *(v4f*)(su + i + REG); v2f cR = su[i + REG + 2];
            v2f s0 = aL + lo2(aC) + hi2(aC) + bL + lo2(bC) + hi2(bC) + cL + lo2(cC) + hi2(cC);
            v2f s1 = lo2(aC) + hi2(aC) + aR + lo2(bC) + hi2(bC) + bR + lo2(cC) + hi2(cC) + cR;
            int gl = (gi0 + li - HALO_L) * WW + (gj0 + 2 * ljp - HALO_L);
            float* o1 = out + (size_t)bimg * 2 * HW + gl;
            *(float2*)o1        = make_float2(s0.x * inv9, s1.x * inv9);
            *(float2*)(o1 + HW) = make_float2(s0.y * inv9, s1.y * inv9);
        }
    }
}

// --------------------------------------------------------------- launch ---
extern "C" void kernel_launch(void* const* d_in, const int* in_sizes, int n_in,
                              void* d_out, int out_size, void* d_ws, size_t ws_size,
                              hipStream_t stream) {
    const float* x     = (const float*)d_in[0];
    const float* lam   = (const float*)d_in[1];
    const float* tau   = (const float*)d_in[2];
    const float* theta = (const float*)d_in[3];
    const float* wx    = (const float*)d_in[4];
    const float* wy    = (const float*)d_in[5];
    float* out = (float*)d_out;

    float*  ws = (float*)d_ws;
    v2f*    ug = (v2f*)ws;                            // 8 MB
    float4* pg = (float4*)(ws + (size_t)2 * NTOT);    // 16 MB

    for (int c = 0; c < 4; ++c) {
        int phase = (c == 0) ? 0 : (c == 3) ? 2 : 1;
        k_fused<<<dim3(NBLK), dim3(TPB), 0, stream>>>(
            x, ug, pg, lam, tau, theta, wx, wy, out, phase);
    }
}

// Round 10
// 433.516 us; speedup vs baseline: 1.1258x; 1.1258x over previous
//
#include <hip/hip_runtime.h>

// TV-L1 optical flow, B=4, 512x512, 20 iters — temporal blocking (ghost zones)
// R10 = R6 structure + pixel-PAIR processing, mirrors sized for the 128-VGPR
// cap (R9 post-mortem: TPB=512 mirrors needed ~180 VGPRs -> 570 MB of spill
// traffic; TPB=1024 / 4 slots needs ~120 -> fits).
//   256 blocks x 1024 threads; 64x64 tile, 80x80 region (halo L=6/R=10),
//   5 fused iterations/launch, 4 launches. Each thread owns 4 pixel-pair
//   slots (3200 pairs); u/pa/pb own-pair state mirrored in VGPRs; neighbor
//   LDS traffic as aligned b128/b64 (~0.73 LDS-pipe cyc/px-iter vs R6 1.2).
// LDS: su,spa,spb = 3 x 6400 x 8B = 153.6 KB. Row-only cone guards
// (R6-validated). Zero-padding via forcing u=p=0 off-image (pair-uniform).
// Last kernel skips the dead 20th p-update and fuses the 3x3 avgpool.

typedef float v2f __attribute__((ext_vector_type(2)));
typedef float v4f __attribute__((ext_vector_type(4)));

#define HH 512
#define WW 512
#define BB 4
constexpr int HW   = HH * WW;
constexpr int NTOT = BB * HW;
constexpr float EPS = 1e-8f;

#define T 64            // output tile edge
#define HALO_L 6        // left/top halo
#define REG 80          // region edge = 64 + 6 + 10
#define NPX (REG * REG) // 6400
#define NPAIR 3200      // pixel pairs per region
#define PPR 40          // pairs per row
#define TPB 1024        // 16 waves -> hard 128-VGPR cap; budget ~120
#define SLOTS 4         // ceil(3200/1024); slot 3: tid<128 valid
#define NBLK 256        // 4 images x 8x8 tiles
#define XR 84           // x1 staging row stride (even, float2-friendly)
#define XROWS 82
#define XN (XR * XROWS) // 6888 floats = 27.6 KB (aliases spa)
#define XPAIRS (XN / 2) // 3444
#define XPPR 42         // staging pairs per row
#define XSLOTS 4

__device__ __forceinline__ v2f lo2(v4f v) { v2f r; r.x = v.x; r.y = v.y; return r; }
__device__ __forceinline__ v2f hi2(v4f v) { v2f r; r.x = v.z; r.y = v.w; return r; }

// phase: 0 = first (u,p zero-init, write back), 1 = middle (load, write
// back), 2 = last (load, 5 u- + 4 p-phases, fused avgpool -> out).
__global__ void __launch_bounds__(TPB)
k_fused(const float* __restrict__ x,
        v2f* __restrict__ ug, float4* __restrict__ pg,
        const float* __restrict__ lam_p, const float* __restrict__ tau_p,
        const float* __restrict__ theta_p,
        const float* __restrict__ wxp, const float* __restrict__ wyp,
        float* __restrict__ out, int phase)
{
    __shared__ __align__(16) v2f su[NPX];    // (u1,u2)
    __shared__ __align__(16) v2f spa[NPX];   // (p11,p21); aliases x1 staging
    __shared__ __align__(16) v2f spb[NPX];   // (p12,p22)  -> 153.6 KB

    const int tid  = threadIdx.x;
    const int blk  = blockIdx.x;
    const int bimg = blk >> 6;
    const int t    = blk & 63;
    const int gi0  = (t >> 3) * T;
    const int gj0  = (t & 7) * T;

    const float lam = lam_p[0], theta = theta_p[0];
    const float r   = tau_p[0] / theta;
    const float tl  = theta * lam;
    const float wx0 = wxp[0], wx1 = wxp[1], wx2 = wxp[2];
    const float wy0 = wyp[0], wy1 = wyp[1], wy2 = wyp[2];

    const int gbase = bimg * HW;
    const float* x0p = x + (size_t)bimg * 2 * HW;
    const float* x1p = x0p + HW;

    int  lis[SLOTS];
    unsigned inbm = 0;                          // bit s = pair in-image
    v4f  ru4[SLOTS], rpa4[SLOTS], rpb4[SLOTS];  // own-pair mirrors
    v2f  x0v[SLOTS];                            // dies after pass 2

    // ---- pass 1a: stage x1 (84x82, zero-padded, float2) into spa ---------
    float* stg = (float*)spa;
    #pragma unroll
    for (int s = 0; s < XSLOTS; ++s) {
        int ip = tid + s * TPB;
        if (ip < XPAIRS) {
            int li = ip / XPPR, ljp = ip - li * XPPR;
            int gi = gi0 + li - (HALO_L + 1);        // rows gi0-7 .. gi0+74
            int gj = gj0 + 2 * ljp - (HALO_L + 2);   // cols gj0-8 .. gj0+74 (even)
            float2 v = make_float2(0.f, 0.f);
            if (((unsigned)gi < HH) & ((unsigned)gj < WW))
                v = *(const float2*)(x1p + gi * WW + gj);
            ((float2*)stg)[ip] = v;
        }
    }
    // ---- pass 1b: per-slot indices + state loads into mirrors ------------
    #pragma unroll
    for (int s = 0; s < SLOTS; ++s) {
        int p = tid + s * TPB;
        lis[s] = 255;
        v4f z4; z4.x = z4.y = z4.z = z4.w = 0.f;
        ru4[s] = z4; rpa4[s] = z4; rpb4[s] = z4;
        x0v[s] = (v2f)(0.f);
        if (p < NPAIR) {
            int li = p / PPR, ljp = p - li * PPR;
            lis[s] = li;
            int gi = gi0 + li - HALO_L, gj = gj0 + 2 * ljp - HALO_L;  // gj even
            bool in = ((unsigned)gi < HH) & ((unsigned)gj < WW);      // pair-uniform
            if (in) {
                inbm |= (1u << s);
                int gl = gi * WW + gj;
                x0v[s] = *(const v2f*)(x0p + gl);
                if (phase != 0) {
                    ru4[s] = *(const v4f*)(ug + gbase + gl);
                    float4 q0 = pg[gbase + gl];
                    float4 q1 = pg[gbase + gl + 1];
                    v4f pa; pa.x = q0.x; pa.y = q0.y; pa.z = q1.x; pa.w = q1.y;
                    v4f pb; pb.x = q0.z; pb.y = q0.w; pb.z = q1.z; pb.w = q1.w;
                    rpa4[s] = pa; rpb4[s] = pb;
                }
            }
        }
    }
    __syncthreads();

    // ---- pass 2: statics per pair, exact R6 expression order -------------
    v4f  g4[SLOTS];                  // (gx0,gy0,gx1,gy1)
    v2f  rc2[SLOTS], th2[SLOTS], nv2[SLOTS];
    #pragma unroll
    for (int s = 0; s < SLOTS; ++s) {
        int p = tid + s * TPB;
        if (p < NPAIR) {
            int li = lis[s], ljp = p - li * PPR;
            int sc = (li + 1) * XR + 2 * ljp + 2;    // px0 center in stg
            // taps: rows sc-XR, sc, sc+XR; cols -1..+2 via three float2 loads
            float2 tA = *(const float2*)(stg + sc - XR - 2);
            float2 tB = *(const float2*)(stg + sc - XR);
            float2 tC = *(const float2*)(stg + sc - XR + 2);
            float2 mA = *(const float2*)(stg + sc - 2);
            float2 mB = *(const float2*)(stg + sc);
            float2 mC = *(const float2*)(stg + sc + 2);
            float2 bA = *(const float2*)(stg + sc + XR - 2);
            float2 bB = *(const float2*)(stg + sc + XR);
            float2 bC = *(const float2*)(stg + sc + XR + 2);
            const float c6 = 1.f / 6.f;
            // px0: a00=tA.y a01=tB.x a02=tB.y / a10=mA.y a11=mB.x a12=mB.y
            //      a20=bA.y a21=bB.x a22=bB.y
            float gx0 = c6 * (-tA.y + tB.y - 2.f * mA.y + 2.f * mB.y - bA.y + bB.y);
            float gy0 = c6 * (-tA.y - 2.f * tB.x - tB.y + bA.y + 2.f * bB.x + bB.y);
            // px1: shift one col right
            float gx1 = c6 * (-tB.x + tC.x - 2.f * mB.x + 2.f * mC.x - bB.x + bC.x);
            float gy1 = c6 * (-tB.x - 2.f * tB.y - tC.x + bB.x + 2.f * bB.y + bC.x);
            float nm0 = gx0 * gx0 + gy0 * gy0 + EPS;
            float nm1 = gx1 * gx1 + gy1 * gy1 + EPS;
            v4f g; g.x = gx0; g.y = gy0; g.z = gx1; g.w = gy1;
            g4[s] = g;
            v2f rc; rc.x = mB.x - x0v[s].x; rc.y = mB.y - x0v[s].y;
            rc2[s] = rc;
            v2f th; th.x = tl * nm0; th.y = tl * nm1;
            th2[s] = th;
            v2f nv; nv.x = __builtin_amdgcn_rcpf(nm0); nv.y = __builtin_amdgcn_rcpf(nm1);
            nv2[s] = nv;
        }
    }
    __syncthreads();

    // ---- pass 3: fill LDS state (overwrites staging) ---------------------
    #pragma unroll
    for (int s = 0; s < SLOTS; ++s) {
        int p = tid + s * TPB;
        if (p < NPAIR) {
            int i = 2 * p;
            *(v4f*)(su  + i) = ru4[s];
            *(v4f*)(spa + i) = rpa4[s];
            *(v4f*)(spb + i) = rpb4[s];
        }
    }
    __syncthreads();

    // ---- 5 fused iterations ---------------------------------------------
    for (int k = 1; k <= 5; ++k) {
        // u-phase rows [k, REG-2k]; all columns (cone-safe, R6-validated)
        const int lo = k, hi_u = REG - 2 * k;
        #pragma unroll
        for (int s = 0; s < SLOTS; ++s) {
            int li = lis[s];
            if (li < lo || li > hi_u) continue;
            int i = 2 * (tid + s * TPB);
            v4f u = ru4[s];
            float rho0 = rc2[s].x + g4[s].x * u.x + g4[s].y * u.y;
            float rho1 = rc2[s].y + g4[s].z * u.z + g4[s].w * u.w;
            float d0 = (fabsf(rho0) < th2[s].x) ? rho0 * nv2[s].x : copysignf(tl, rho0);
            float d1 = (fabsf(rho1) < th2[s].y) ? rho1 * nv2[s].y : copysignf(tl, rho1);
            v2f pal = spa[i - 1];
            v2f par = spa[i + 2];
            v4f pbt = *(v4f*)(spb + i - REG);
            v4f pbb = *(v4f*)(spb + i + REG);
            v4f pac = rpa4[s], pbc = rpb4[s];
            v2f div0 = wx0 * pal      + wx1 * lo2(pac) + wx2 * hi2(pac)
                     + wy0 * lo2(pbt) + wy1 * lo2(pbc) + wy2 * lo2(pbb);
            v2f div1 = wx0 * lo2(pac) + wx1 * hi2(pac) + wx2 * par
                     + wy0 * hi2(pbt) + wy1 * hi2(pbc) + wy2 * hi2(pbb);
            v2f nu0 = lo2(u); nu0.x -= d0 * g4[s].x; nu0.y -= d0 * g4[s].y;
            v2f nu1 = hi2(u); nu1.x -= d1 * g4[s].z; nu1.y -= d1 * g4[s].w;
            nu0 += theta * div0;
            nu1 += theta * div1;
            if (!((inbm >> s) & 1u)) { nu0 = (v2f)(0.f); nu1 = (v2f)(0.f); }
            v4f nu; nu.x = nu0.x; nu.y = nu0.y; nu.z = nu1.x; nu.w = nu1.y;
            ru4[s] = nu;
            *(v4f*)(su + i) = nu;
        }
        __syncthreads();
        if (phase == 2 && k == 5) break;   // 20th p-update is dead code

        // p-phase rows [k, REG-1-2k]
        const int hi_p = REG - 1 - 2 * k;
        #pragma unroll
        for (int s = 0; s < SLOTS; ++s) {
            int li = lis[s];
            if (li < lo || li > hi_p) continue;
            int i = 2 * (tid + s * TPB);
            v4f uc = ru4[s];
            v2f uE1 = su[i + 2];                 // right neighbor of px1
            v4f uS  = *(v4f*)(su + i + REG);
            v2f gx0 = hi2(uc) - lo2(uc);
            v2f gx1 = uE1 - hi2(uc);
            v2f gy0 = lo2(uS) - lo2(uc);
            v2f gy1 = hi2(uS) - hi2(uc);
            float dn00 = 1.f + r * (fabsf(gx0.x) + fabsf(gy0.x));
            float dn01 = 1.f + r * (fabsf(gx0.y) + fabsf(gy0.y));
            float dn10 = 1.f + r * (fabsf(gx1.x) + fabsf(gy1.x));
            float dn11 = 1.f + r * (fabsf(gx1.y) + fabsf(gy1.y));
            v2f id0; id0.x = __builtin_amdgcn_rcpf(dn00); id0.y = __builtin_amdgcn_rcpf(dn01);
            v2f id1; id1.x = __builtin_amdgcn_rcpf(dn10); id1.y = __builtin_amdgcn_rcpf(dn11);
            v2f npa0 = (lo2(rpa4[s]) + r * gx0) * id0;
            v2f npa1 = (hi2(rpa4[s]) + r * gx1) * id1;
            v2f npb0 = (lo2(rpb4[s]) + r * gy0) * id0;
            v2f npb1 = (hi2(rpb4[s]) + r * gy1) * id1;
            if (!((inbm >> s) & 1u)) {
                npa0 = (v2f)(0.f); npa1 = (v2f)(0.f);
                npb0 = (v2f)(0.f); npb1 = (v2f)(0.f);
            }
            v4f npa; npa.x = npa0.x; npa.y = npa0.y; npa.z = npa1.x; npa.w = npa1.y;
            v4f npb; npb.x = npb0.x; npb.y = npb0.y; npb.z = npb1.x; npb.w = npb1.y;
            rpa4[s] = npa; rpb4[s] = npb;
            *(v4f*)(spa + i) = npa;
            *(v4f*)(spb + i) = npb;
        }
        __syncthreads();
    }

    // ---- epilogue --------------------------------------------------------
    if (phase != 2) {
        // write back interior pairs (li in [6,69], ljp in [3,34])
        #pragma unroll
        for (int s = 0; s < SLOTS; ++s) {
            int p = tid + s * TPB;
            int li = lis[s];
            if ((unsigned)(li - HALO_L) >= T) continue;
            int ljp = p - li * PPR;
            if ((unsigned)(ljp - 3) >= 32) continue;
            int gl = (gi0 + li - HALO_L) * WW + (gj0 + 2 * ljp - HALO_L);
            *(v4f*)(ug + gbase + gl) = ru4[s];
            v4f pa = rpa4[s], pb = rpb4[s];
            pg[gbase + gl]     = make_float4(pa.x, pa.y, pb.x, pb.y);
            pg[gbase + gl + 1] = make_float4(pa.z, pa.w, pb.z, pb.w);
        }
    } else {
        // fused avgpool(3,1,1, /9 always) on u^20
        const float inv9 = 1.f / 9.f;
        #pragma unroll
        for (int s = 0; s < SLOTS; ++s) {
            int p = tid + s * TPB;
            int li = lis[s];
            if ((unsigned)(li - HALO_L) >= T) continue;
            int ljp = p - li * PPR;
            if ((unsigned)(ljp - 3) >= 32) continue;
            int i = 2 * p;
            v2f aL = su[i - REG - 1]; v4f aC = *(v4f*)(su + i - REG); v2f aR = su[i - REG + 2];
            v2f bL = su[i - 1];       v4f bC = ru4[s];                v2f bR = su[i + 2];
            v2f cL = su[i + REG - 1]; v4f cC = *(v4f*)(su + i + REG); v2f cR = su[i + REG + 2];
            v2f s0 = aL + lo2(aC) + hi2(aC) + bL + lo2(bC) + hi2(bC)
                   + cL + lo2(cC) + hi2(cC);
            v2f s1 = lo2(aC) + hi2(aC) + aR + lo2(bC) + hi2(bC) + bR
                   + lo2(cC) + hi2(cC) + cR;
            int gl = (gi0 + li - HALO_L) * WW + (gj0 + 2 * ljp - HALO_L);
            float* o1 = out + (size_t)bimg * 2 * HW + gl;
            *(float2*)o1        = make_float2(s0.x * inv9, s1.x * inv9);
            *(float2*)(o1 + HW) = make_float2(s0.y * inv9, s1.y * inv9);
        }
    }
}

// --------------------------------------------------------------- launch ---
extern "C" void kernel_launch(void* const* d_in, const int* in_sizes, int n_in,
                              void* d_out, int out_size, void* d_ws, size_t ws_size,
                              hipStream_t stream) {
    const float* x     = (const float*)d_in[0];
    const float* lam   = (const float*)d_in[1];
    const float* tau   = (const float*)d_in[2];
    const float* theta = (const float*)d_in[3];
    const float* wx    = (const float*)d_in[4];
    const float* wy    = (const float*)d_in[5];
    float* out = (float*)d_out;

    float*  ws = (float*)d_ws;
    v2f*    ug = (v2f*)ws;                            // 8 MB
    float4* pg = (float4*)(ws + (size_t)2 * NTOT);    // 16 MB

    for (int c = 0; c < 4; ++c) {
        int phase = (c == 0) ? 0 : (c == 3) ? 2 : 1;
        k_fused<<<dim3(NBLK), dim3(TPB), 0, stream>>>(
            x, ug, pg, lam, tau, theta, wx, wy, out, phase);
    }
}